// Round 1
// baseline (549.124 us; speedup 1.0000x reference)
//
#include <hip/hip_runtime.h>
#include <hip/hip_bf16.h>

typedef __bf16 bf16;
typedef bf16 bf16x8 __attribute__((ext_vector_type(8)));
typedef bf16 bf16x4 __attribute__((ext_vector_type(4)));
typedef float floatx4 __attribute__((ext_vector_type(4)));

#define B_ 32
#define N_ 196
#define H_ 8
#define D_ 1024
#define DK_ 128
#define BN_ (B_ * N_)   // 6272
#define BH_ (B_ * H_)   // 256
#define NPAD_ 224       // padded N for S rows / Vt rows (multiple of 32, keeps 16B alignment)

__device__ __forceinline__ bf16x8 bzero8() {
  bf16x8 z;
#pragma unroll
  for (int i = 0; i < 8; i++) z[i] = (bf16)0.0f;
  return z;
}

// ---------------------------------------------------------------------------
// f32 -> bf16 convert (vectorized float4 -> bf16x4)
// ---------------------------------------------------------------------------
__global__ __launch_bounds__(256) void cvt_kernel(const float* __restrict__ src,
                                                  bf16* __restrict__ dst, int n4) {
  int i = blockIdx.x * 256 + threadIdx.x;
  if (i >= n4) return;
  float4 v = ((const float4*)src)[i];
  bf16x4 o;
  o[0] = (bf16)v.x;
  o[1] = (bf16)v.y;
  o[2] = (bf16)v.z;
  o[3] = (bf16)v.w;
  *(bf16x4*)(dst + (size_t)i * 4) = o;
}

// ---------------------------------------------------------------------------
// Geometry bias: S[b,h,n,m] = log(max(relu(geo(n,m) . WG_w[h] + WG_b[h]), 1e-6))
// one thread per (b,n,m), all 8 heads
// ---------------------------------------------------------------------------
__global__ __launch_bounds__(256) void geo_kernel(const float* __restrict__ box,
                                                  const float* __restrict__ WGw,
                                                  const float* __restrict__ WGb,
                                                  float* __restrict__ S) {
  __shared__ float4 wsh[128];  // 8 heads x 64 feats = 512 f32 = 128 float4
  if (threadIdx.x < 128) wsh[threadIdx.x] = ((const float4*)WGw)[threadIdx.x];
  __syncthreads();

  int tid = blockIdx.x * 256 + threadIdx.x;
  int b = tid / (N_ * N_);
  int rem = tid - b * (N_ * N_);
  int n = rem / N_;
  int m = rem - n * N_;

  float4 bn = ((const float4*)box)[b * N_ + n];
  float4 bm = ((const float4*)box)[b * N_ + m];
  float cxn = (bn.x + bn.z) * 0.5f, cyn = (bn.y + bn.w) * 0.5f;
  float wn = bn.z - bn.x + 1.0f, hn = bn.w - bn.y + 1.0f;
  float cxm = (bm.x + bm.z) * 0.5f, cym = (bm.y + bm.w) * 0.5f;
  float wm = bm.z - bm.x + 1.0f, hm = bm.w - bm.y + 1.0f;

  float pos[4];
  pos[0] = __logf(fmaxf(fabsf((cxn - cxm) / wn), 1e-3f));
  pos[1] = __logf(fmaxf(fabsf((cyn - cym) / hn), 1e-3f));
  pos[2] = __logf(wn / wm);
  pos[3] = __logf(hn / hm);

  const float dims[8] = {1.0f,          0.4216965034f, 0.1778279410f, 0.0749894209f,
                         0.0316227766f, 0.0133352143f, 0.0056234133f, 0.0023713737f};
  float feat[64];
#pragma unroll
  for (int p = 0; p < 4; p++) {
#pragma unroll
    for (int f = 0; f < 8; f++) {
      float a = 100.0f * pos[p] * dims[f];
      feat[p * 8 + f] = __sinf(a);
      feat[32 + p * 8 + f] = __cosf(a);
    }
  }
#pragma unroll
  for (int hh = 0; hh < 8; hh++) {
    float accv = WGb[hh];
#pragma unroll
    for (int g4 = 0; g4 < 16; g4++) {
      float4 wv = wsh[hh * 16 + g4];
      accv += feat[g4 * 4 + 0] * wv.x + feat[g4 * 4 + 1] * wv.y +
              feat[g4 * 4 + 2] * wv.z + feat[g4 * 4 + 3] * wv.w;
    }
    S[((size_t)((b * H_ + hh) * N_ + n)) * NPAD_ + m] = __logf(fmaxf(accv, 1e-6f));
  }
}

// ---------------------------------------------------------------------------
// NT GEMM: C[M,Nd] = A[M,K] * W[Nd,K]^T + bias.  128x128 block tile, 4 waves,
// each wave 64x64 via 4x4 mfma_f32_16x16x32_bf16 frags. M,Nd multiples of 128,
// K multiple of 32 (exact here: 6272x1024x1024).
// MODE 0: store bf16 row-major; MODE 1: store f32 row-major;
// MODE 2: store V transposed per head -> Vt[(b*H+h)*DK + d][NPAD] bf16
// ---------------------------------------------------------------------------
template <int MODE>
__global__ __launch_bounds__(256) void gemm_nt(const bf16* __restrict__ A,
                                               const bf16* __restrict__ W,
                                               const float* __restrict__ bias,
                                               void* __restrict__ Cout, int M, int K,
                                               int Nd) {
  const int wave = threadIdx.x >> 6;
  const int lane = threadIdx.x & 63;
  const int l16 = lane & 15;
  const int quad = lane >> 4;
  const int m0 = blockIdx.x * 128 + (wave >> 1) * 64;
  const int n0 = blockIdx.y * 128 + (wave & 1) * 64;

  floatx4 acc[4][4];
#pragma unroll
  for (int i = 0; i < 4; i++)
#pragma unroll
    for (int j = 0; j < 4; j++)
#pragma unroll
      for (int r = 0; r < 4; r++) acc[i][j][r] = 0.0f;

  const bf16* aptr = A + (size_t)(m0 + l16) * K + quad * 8;
  const bf16* bptr = W + (size_t)(n0 + l16) * K + quad * 8;
  for (int k0 = 0; k0 < K; k0 += 32) {
    bf16x8 af[4], bfv[4];
#pragma unroll
    for (int i = 0; i < 4; i++) af[i] = *(const bf16x8*)(aptr + (size_t)i * 16 * K + k0);
#pragma unroll
    for (int j = 0; j < 4; j++) bfv[j] = *(const bf16x8*)(bptr + (size_t)j * 16 * K + k0);
#pragma unroll
    for (int i = 0; i < 4; i++)
#pragma unroll
      for (int j = 0; j < 4; j++)
        acc[i][j] = __builtin_amdgcn_mfma_f32_16x16x32_bf16(af[i], bfv[j], acc[i][j], 0, 0, 0);
  }

#pragma unroll
  for (int j = 0; j < 4; j++) {
    const int col = n0 + j * 16 + l16;
    const float bv = bias[col];
#pragma unroll
    for (int i = 0; i < 4; i++) {
#pragma unroll
      for (int r = 0; r < 4; r++) {
        const int row = m0 + i * 16 + quad * 4 + r;
        float v = acc[i][j][r] + bv;
        if (MODE == 0) {
          ((bf16*)Cout)[(size_t)row * Nd + col] = (bf16)v;
        } else if (MODE == 1) {
          ((float*)Cout)[(size_t)row * Nd + col] = v;
        } else {
          int b = row / N_;
          int n = row - b * N_;
          int h = col >> 7;
          int d = col & (DK_ - 1);
          ((bf16*)Cout)[((size_t)((b * H_ + h) * DK_ + d)) * NPAD_ + n] = (bf16)v;
        }
      }
    }
  }
}

// ---------------------------------------------------------------------------
// scores: S[bh,n,m] += (Q[b,n,h,:] . K[b,m,h,:]) / sqrt(dk)   (in place over bias)
// grid (2,2,256); bounds-masked at 196.
// ---------------------------------------------------------------------------
__global__ __launch_bounds__(256) void scores_kernel(const bf16* __restrict__ Q,
                                                     const bf16* __restrict__ Kmat,
                                                     float* __restrict__ S) {
  const int bh = blockIdx.z;
  const int b = bh >> 3;
  const int h = bh & 7;
  const int wave = threadIdx.x >> 6;
  const int lane = threadIdx.x & 63;
  const int l16 = lane & 15;
  const int quad = lane >> 4;
  const int n0 = blockIdx.x * 128 + (wave >> 1) * 64;
  const int m0 = blockIdx.y * 128 + (wave & 1) * 64;
  const bf16* qbase = Q + (size_t)b * N_ * D_ + h * DK_ + quad * 8;
  const bf16* kbase = Kmat + (size_t)b * N_ * D_ + h * DK_ + quad * 8;

  floatx4 acc[4][4];
#pragma unroll
  for (int i = 0; i < 4; i++)
#pragma unroll
    for (int j = 0; j < 4; j++)
#pragma unroll
      for (int r = 0; r < 4; r++) acc[i][j][r] = 0.0f;

#pragma unroll
  for (int k0 = 0; k0 < DK_; k0 += 32) {
    bf16x8 af[4], bfv[4];
#pragma unroll
    for (int i = 0; i < 4; i++) {
      int n = n0 + i * 16 + l16;
      af[i] = (n < N_) ? *(const bf16x8*)(qbase + (size_t)n * D_ + k0) : bzero8();
    }
#pragma unroll
    for (int j = 0; j < 4; j++) {
      int m = m0 + j * 16 + l16;
      bfv[j] = (m < N_) ? *(const bf16x8*)(kbase + (size_t)m * D_ + k0) : bzero8();
    }
#pragma unroll
    for (int i = 0; i < 4; i++)
#pragma unroll
      for (int j = 0; j < 4; j++)
        acc[i][j] = __builtin_amdgcn_mfma_f32_16x16x32_bf16(af[i], bfv[j], acc[i][j], 0, 0, 0);
  }

  const float scale = 0.08838834764831845f;  // 1/sqrt(128)
#pragma unroll
  for (int i = 0; i < 4; i++) {
#pragma unroll
    for (int j = 0; j < 4; j++) {
      int m = m0 + j * 16 + l16;
#pragma unroll
      for (int r = 0; r < 4; r++) {
        int n = n0 + i * 16 + quad * 4 + r;
        if (n < N_ && m < N_) {
          size_t idx = ((size_t)bh * N_ + n) * NPAD_ + m;
          S[idx] = S[idx] + acc[i][j][r] * scale;
        }
      }
    }
  }
}

// ---------------------------------------------------------------------------
// softmax over last dim (196), one wave per row, in place (f32)
// ---------------------------------------------------------------------------
__global__ __launch_bounds__(256) void softmax_kernel(float* __restrict__ S) {
  const int bh = blockIdx.y;
  const int n = blockIdx.x * 4 + (threadIdx.x >> 6);
  const int lane = threadIdx.x & 63;
  float* row = S + ((size_t)bh * N_ + n) * NPAD_;
  float v[4];
  float mx = -1e30f;
#pragma unroll
  for (int t = 0; t < 4; t++) {
    int m = lane + t * 64;
    v[t] = (m < N_) ? row[m] : -1e30f;
    mx = fmaxf(mx, v[t]);
  }
#pragma unroll
  for (int off = 32; off > 0; off >>= 1) mx = fmaxf(mx, __shfl_xor(mx, off, 64));
  float s = 0.0f;
#pragma unroll
  for (int t = 0; t < 4; t++) {
    v[t] = __expf(v[t] - mx);
    s += v[t];
  }
#pragma unroll
  for (int off = 32; off > 0; off >>= 1) s += __shfl_xor(s, off, 64);
  const float inv = 1.0f / s;
#pragma unroll
  for (int t = 0; t < 4; t++) {
    int m = lane + t * 64;
    if (m < N_) row[m] = v[t] * inv;
  }
}

// ---------------------------------------------------------------------------
// PV: AO[b,n,h,d] = sum_m P[bh,n,m] * V[b,m,h,d]   (V pre-transposed: Vt[bh*DK+d][NPAD])
// grid (2,1,256)
// ---------------------------------------------------------------------------
__global__ __launch_bounds__(256) void pv_kernel(const float* __restrict__ P,
                                                 const bf16* __restrict__ Vt,
                                                 bf16* __restrict__ AO) {
  const int bh = blockIdx.z;
  const int b = bh >> 3;
  const int h = bh & 7;
  const int wave = threadIdx.x >> 6;
  const int lane = threadIdx.x & 63;
  const int l16 = lane & 15;
  const int quad = lane >> 4;
  const int n0 = blockIdx.x * 128 + (wave >> 1) * 64;
  const int d0 = (wave & 1) * 64;
  const float* pbase = P + (size_t)bh * N_ * NPAD_;
  const bf16* vbase = Vt + (size_t)bh * DK_ * NPAD_ + quad * 8;

  floatx4 acc[4][4];
#pragma unroll
  for (int i = 0; i < 4; i++)
#pragma unroll
    for (int j = 0; j < 4; j++)
#pragma unroll
      for (int r = 0; r < 4; r++) acc[i][j][r] = 0.0f;

#pragma unroll
  for (int k0 = 0; k0 < NPAD_; k0 += 32) {  // 7 steps, masked past 196
    bf16x8 af[4], bfv[4];
#pragma unroll
    for (int i = 0; i < 4; i++) {
      int n = n0 + i * 16 + l16;
      bf16x8 a = bzero8();
      if (n < N_) {
        const float* sp = pbase + (size_t)n * NPAD_ + k0 + quad * 8;
#pragma unroll
        for (int jj = 0; jj < 8; jj++) {
          int m = k0 + quad * 8 + jj;
          float pv = (m < N_) ? sp[jj] : 0.0f;
          a[jj] = (bf16)pv;
        }
      }
      af[i] = a;
    }
#pragma unroll
    for (int j = 0; j < 4; j++) {
      int d = d0 + j * 16 + l16;
      bfv[j] = *(const bf16x8*)(vbase + (size_t)d * NPAD_ + k0);
    }
#pragma unroll
    for (int i = 0; i < 4; i++)
#pragma unroll
      for (int j = 0; j < 4; j++)
        acc[i][j] = __builtin_amdgcn_mfma_f32_16x16x32_bf16(af[i], bfv[j], acc[i][j], 0, 0, 0);
  }

#pragma unroll
  for (int i = 0; i < 4; i++) {
#pragma unroll
    for (int j = 0; j < 4; j++) {
      int d = d0 + j * 16 + l16;
#pragma unroll
      for (int r = 0; r < 4; r++) {
        int n = n0 + i * 16 + quad * 4 + r;
        if (n < N_) {
          AO[((size_t)(b * N_ + n)) * D_ + h * DK_ + d] = (bf16)acc[i][j][r];
        }
      }
    }
  }
}

// ---------------------------------------------------------------------------
extern "C" void kernel_launch(void* const* d_in, const int* in_sizes, int n_in,
                              void* d_out, int out_size, void* d_ws, size_t ws_size,
                              hipStream_t stream) {
  const float* xq = (const float*)d_in[0];
  const float* xk = (const float*)d_in[1];
  const float* xv = (const float*)d_in[2];
  const float* box = (const float*)d_in[3];
  const float* Wq = (const float*)d_in[4];
  const float* bq = (const float*)d_in[5];
  const float* Wk = (const float*)d_in[6];
  const float* bk = (const float*)d_in[7];
  const float* Wv = (const float*)d_in[8];
  const float* bv = (const float*)d_in[9];
  const float* Wo = (const float*)d_in[10];
  const float* bo = (const float*)d_in[11];
  const float* WGw = (const float*)d_in[12];
  const float* WGb = (const float*)d_in[13];

  size_t off = 0;
  char* wsc = (char*)d_ws;
  auto alloc = [&](size_t bytes) -> void* {
    void* p = wsc + off;
    off += (bytes + 255) & ~(size_t)255;
    return p;
  };
  bf16* xq_b = (bf16*)alloc((size_t)BN_ * D_ * 2);
  bf16* xk_b = (bf16*)alloc((size_t)BN_ * D_ * 2);
  bf16* xv_b = (bf16*)alloc((size_t)BN_ * D_ * 2);
  bf16* wq_b = (bf16*)alloc((size_t)D_ * D_ * 2);
  bf16* wk_b = (bf16*)alloc((size_t)D_ * D_ * 2);
  bf16* wv_b = (bf16*)alloc((size_t)D_ * D_ * 2);
  bf16* wo_b = (bf16*)alloc((size_t)D_ * D_ * 2);
  bf16* q_b = (bf16*)alloc((size_t)BN_ * D_ * 2);
  bf16* k_b = (bf16*)alloc((size_t)BN_ * D_ * 2);
  bf16* vt_b = (bf16*)alloc((size_t)BH_ * DK_ * NPAD_ * 2);
  bf16* ao_b = (bf16*)alloc((size_t)BN_ * D_ * 2);
  float* S = (float*)alloc((size_t)BH_ * N_ * NPAD_ * 4);

  const int n4x = BN_ * D_ / 4;  // 1605632
  const int n4w = D_ * D_ / 4;   // 262144
  cvt_kernel<<<n4x / 256, 256, 0, stream>>>(xq, xq_b, n4x);
  cvt_kernel<<<n4x / 256, 256, 0, stream>>>(xk, xk_b, n4x);
  cvt_kernel<<<n4x / 256, 256, 0, stream>>>(xv, xv_b, n4x);
  cvt_kernel<<<n4w / 256, 256, 0, stream>>>(Wq, wq_b, n4w);
  cvt_kernel<<<n4w / 256, 256, 0, stream>>>(Wk, wk_b, n4w);
  cvt_kernel<<<n4w / 256, 256, 0, stream>>>(Wv, wv_b, n4w);
  cvt_kernel<<<n4w / 256, 256, 0, stream>>>(Wo, wo_b, n4w);

  geo_kernel<<<(B_ * N_ * N_) / 256, 256, 0, stream>>>(box, WGw, WGb, S);

  dim3 gproj(BN_ / 128, D_ / 128, 1);  // (49, 8)
  gemm_nt<0><<<gproj, 256, 0, stream>>>(xq_b, wq_b, bq, q_b, BN_, D_, D_);
  gemm_nt<0><<<gproj, 256, 0, stream>>>(xk_b, wk_b, bk, k_b, BN_, D_, D_);
  gemm_nt<2><<<gproj, 256, 0, stream>>>(xv_b, wv_b, bv, vt_b, BN_, D_, D_);

  scores_kernel<<<dim3(2, 2, BH_), 256, 0, stream>>>(q_b, k_b, S);
  softmax_kernel<<<dim3(49, BH_, 1), 256, 0, stream>>>(S);
  pv_kernel<<<dim3(2, 1, BH_), 256, 0, stream>>>(S, vt_b, ao_b);

  gemm_nt<1><<<gproj, 256, 0, stream>>>(ao_b, wo_b, bo, d_out, BN_, D_, D_);
}

// Round 2
// 409.136 us; speedup vs baseline: 1.3422x; 1.3422x over previous
//
#include <hip/hip_runtime.h>
#include <hip/hip_bf16.h>

typedef __bf16 bf16;
typedef bf16 bf16x8 __attribute__((ext_vector_type(8)));
typedef bf16 bf16x4 __attribute__((ext_vector_type(4)));
typedef float floatx4 __attribute__((ext_vector_type(4)));

#define B_ 32
#define N_ 196
#define H_ 8
#define D_ 1024
#define DK_ 128
#define BN_ (B_ * N_)   // 6272
#define BH_ (B_ * H_)   // 256
#define NPAD_ 224       // padded N for S rows / Vt rows

typedef __attribute__((address_space(3))) unsigned int lds_uint;
typedef const __attribute__((address_space(1))) unsigned int glb_uint;

__device__ __forceinline__ void async_copy16(const bf16* g, bf16* l) {
  __builtin_amdgcn_global_load_lds((glb_uint*)g, (lds_uint*)l, 16, 0, 0);
}

__device__ __forceinline__ bf16x8 bzero8() {
  bf16x8 z;
#pragma unroll
  for (int i = 0; i < 8; i++) z[i] = (bf16)0.0f;
  return z;
}

// ---------------------------------------------------------------------------
// f32 -> bf16 convert (vectorized float4 -> bf16x4)
// ---------------------------------------------------------------------------
__global__ __launch_bounds__(256) void cvt_kernel(const float* __restrict__ src,
                                                  bf16* __restrict__ dst, int n4) {
  int i = blockIdx.x * 256 + threadIdx.x;
  if (i >= n4) return;
  float4 v = ((const float4*)src)[i];
  bf16x4 o;
  o[0] = (bf16)v.x;
  o[1] = (bf16)v.y;
  o[2] = (bf16)v.z;
  o[3] = (bf16)v.w;
  *(bf16x4*)(dst + (size_t)i * 4) = o;
}

// ---------------------------------------------------------------------------
// Geometry bias: S[b,h,n,m] = log(max(relu(geo(n,m) . WG_w[h] + WG_b[h]), 1e-6))
// ---------------------------------------------------------------------------
__global__ __launch_bounds__(256) void geo_kernel(const float* __restrict__ box,
                                                  const float* __restrict__ WGw,
                                                  const float* __restrict__ WGb,
                                                  float* __restrict__ S) {
  __shared__ float4 wsh[128];  // 8 heads x 64 feats
  if (threadIdx.x < 128) wsh[threadIdx.x] = ((const float4*)WGw)[threadIdx.x];
  __syncthreads();

  int tid = blockIdx.x * 256 + threadIdx.x;
  int b = tid / (N_ * N_);
  int rem = tid - b * (N_ * N_);
  int n = rem / N_;
  int m = rem - n * N_;

  float4 bn = ((const float4*)box)[b * N_ + n];
  float4 bm = ((const float4*)box)[b * N_ + m];
  float cxn = (bn.x + bn.z) * 0.5f, cyn = (bn.y + bn.w) * 0.5f;
  float wn = bn.z - bn.x + 1.0f, hn = bn.w - bn.y + 1.0f;
  float cxm = (bm.x + bm.z) * 0.5f, cym = (bm.y + bm.w) * 0.5f;
  float wm = bm.z - bm.x + 1.0f, hm = bm.w - bm.y + 1.0f;

  float pos[4];
  pos[0] = __logf(fmaxf(fabsf((cxn - cxm) / wn), 1e-3f));
  pos[1] = __logf(fmaxf(fabsf((cyn - cym) / hn), 1e-3f));
  pos[2] = __logf(wn / wm);
  pos[3] = __logf(hn / hm);

  const float dims[8] = {1.0f,          0.4216965034f, 0.1778279410f, 0.0749894209f,
                         0.0316227766f, 0.0133352143f, 0.0056234133f, 0.0023713737f};
  float feat[64];
#pragma unroll
  for (int p = 0; p < 4; p++) {
#pragma unroll
    for (int f = 0; f < 8; f++) {
      float a = 100.0f * pos[p] * dims[f];
      feat[p * 8 + f] = __sinf(a);
      feat[32 + p * 8 + f] = __cosf(a);
    }
  }
#pragma unroll
  for (int hh = 0; hh < 8; hh++) {
    float accv = WGb[hh];
#pragma unroll
    for (int g4 = 0; g4 < 16; g4++) {
      float4 wv = wsh[hh * 16 + g4];
      accv += feat[g4 * 4 + 0] * wv.x + feat[g4 * 4 + 1] * wv.y +
              feat[g4 * 4 + 2] * wv.z + feat[g4 * 4 + 3] * wv.w;
    }
    S[((size_t)((b * H_ + hh) * N_ + n)) * NPAD_ + m] = __logf(fmaxf(accv, 1e-6f));
  }
}

// ---------------------------------------------------------------------------
// NT GEMM w/ LDS staging (m97 structure): C[M,Nd] = A[M,K]*W[Nd,K]^T + bias.
// 128x128 block tile, BK=32, global_load_lds width=16, 2-barrier K-loop.
// M,Nd multiples of 128, K multiple of 32.
// MODE 0: store bf16 row-major; MODE 1: store f32 row-major;
// MODE 2: store V transposed per head -> Vt[(b*H+h)*DK + d][NPAD] bf16
// ---------------------------------------------------------------------------
template <int MODE>
__global__ __launch_bounds__(256) void gemm_nt(const bf16* __restrict__ A,
                                               const bf16* __restrict__ W,
                                               const float* __restrict__ bias,
                                               void* __restrict__ Cout, int M, int K,
                                               int Nd) {
  __shared__ bf16 As[128 * 32];
  __shared__ bf16 Bs[128 * 32];

  const int wave = threadIdx.x >> 6;
  const int lane = threadIdx.x & 63;
  const int l16 = lane & 15;
  const int quad = lane >> 4;

  const bf16* gA = A + (size_t)blockIdx.x * 128 * K;
  const bf16* gB = W + (size_t)blockIdx.y * 128 * K;

  // staging: wave w loads segments 2w, 2w+1 (16 rows each) of A-tile and B-tile.
  // lane -> (row = seg*16 + lane/4, col = (lane%4)*8); lds offset = seg*512 + lane*8 elems
  const int srow = lane >> 2;        // 0..15
  const int scol = (lane & 3) * 8;   // 0,8,16,24
  const int seg0 = wave * 2;
  const size_t gOffA0 = (size_t)(seg0 * 16 + srow) * K + scol;
  const size_t gOffA1 = (size_t)(seg0 * 16 + 16 + srow) * K + scol;
  bf16* lA0 = As + seg0 * 512 + lane * 8;
  bf16* lA1 = As + (seg0 + 1) * 512 + lane * 8;
  bf16* lB0 = Bs + seg0 * 512 + lane * 8;
  bf16* lB1 = Bs + (seg0 + 1) * 512 + lane * 8;

  floatx4 acc[4][4];
#pragma unroll
  for (int i = 0; i < 4; i++)
#pragma unroll
    for (int j = 0; j < 4; j++)
#pragma unroll
      for (int r = 0; r < 4; r++) acc[i][j][r] = 0.0f;

  // prologue stage k0=0
  async_copy16(gA + gOffA0, lA0);
  async_copy16(gA + gOffA1, lA1);
  async_copy16(gB + gOffA0, lB0);
  async_copy16(gB + gOffA1, lB1);

  const bf16* rA = As + ((wave >> 1) * 64 + l16) * 32 + quad * 8;
  const bf16* rB = Bs + ((wave & 1) * 64 + l16) * 32 + quad * 8;

  for (int k0 = 0; k0 < K; k0 += 32) {
    __syncthreads();  // staging for this k0 visible
    bf16x8 af[4], bfv[4];
#pragma unroll
    for (int i = 0; i < 4; i++) af[i] = *(const bf16x8*)(rA + i * 16 * 32);
#pragma unroll
    for (int j = 0; j < 4; j++) bfv[j] = *(const bf16x8*)(rB + j * 16 * 32);
    __syncthreads();  // all waves done reading LDS
    if (k0 + 32 < K) {
      const bf16* gAn = gA + k0 + 32;
      const bf16* gBn = gB + k0 + 32;
      async_copy16(gAn + gOffA0, lA0);
      async_copy16(gAn + gOffA1, lA1);
      async_copy16(gBn + gOffA0, lB0);
      async_copy16(gBn + gOffA1, lB1);
    }
#pragma unroll
    for (int i = 0; i < 4; i++)
#pragma unroll
      for (int j = 0; j < 4; j++)
        acc[i][j] = __builtin_amdgcn_mfma_f32_16x16x32_bf16(af[i], bfv[j], acc[i][j], 0, 0, 0);
  }

  const int m0 = blockIdx.x * 128 + (wave >> 1) * 64;
  const int n0 = blockIdx.y * 128 + (wave & 1) * 64;
#pragma unroll
  for (int j = 0; j < 4; j++) {
    const int col = n0 + j * 16 + l16;
    const float bv = bias[col];
#pragma unroll
    for (int i = 0; i < 4; i++) {
#pragma unroll
      for (int r = 0; r < 4; r++) {
        const int row = m0 + i * 16 + quad * 4 + r;
        float v = acc[i][j][r] + bv;
        if (MODE == 0) {
          ((bf16*)Cout)[(size_t)row * Nd + col] = (bf16)v;
        } else if (MODE == 1) {
          ((float*)Cout)[(size_t)row * Nd + col] = v;
        } else {
          int b = row / N_;
          int n = row - b * N_;
          int h = col >> 7;
          int d = col & (DK_ - 1);
          ((bf16*)Cout)[((size_t)((b * H_ + h) * DK_ + d)) * NPAD_ + n] = (bf16)v;
        }
      }
    }
  }
}

// ---------------------------------------------------------------------------
// scores: S[bh,n,m] += (Q[b,n,h,:] . K[b,m,h,:]) / sqrt(dk)   (in place over bias)
// ---------------------------------------------------------------------------
__global__ __launch_bounds__(256) void scores_kernel(const bf16* __restrict__ Q,
                                                     const bf16* __restrict__ Kmat,
                                                     float* __restrict__ S) {
  const int bh = blockIdx.z;
  const int b = bh >> 3;
  const int h = bh & 7;
  const int wave = threadIdx.x >> 6;
  const int lane = threadIdx.x & 63;
  const int l16 = lane & 15;
  const int quad = lane >> 4;
  const int n0 = blockIdx.x * 128 + (wave >> 1) * 64;
  const int m0 = blockIdx.y * 128 + (wave & 1) * 64;
  const bf16* qbase = Q + (size_t)b * N_ * D_ + h * DK_ + quad * 8;
  const bf16* kbase = Kmat + (size_t)b * N_ * D_ + h * DK_ + quad * 8;

  floatx4 acc[4][4];
#pragma unroll
  for (int i = 0; i < 4; i++)
#pragma unroll
    for (int j = 0; j < 4; j++)
#pragma unroll
      for (int r = 0; r < 4; r++) acc[i][j][r] = 0.0f;

#pragma unroll
  for (int k0 = 0; k0 < DK_; k0 += 32) {
    bf16x8 af[4], bfv[4];
#pragma unroll
    for (int i = 0; i < 4; i++) {
      int n = n0 + i * 16 + l16;
      af[i] = (n < N_) ? *(const bf16x8*)(qbase + (size_t)n * D_ + k0) : bzero8();
    }
#pragma unroll
    for (int j = 0; j < 4; j++) {
      int m = m0 + j * 16 + l16;
      bfv[j] = (m < N_) ? *(const bf16x8*)(kbase + (size_t)m * D_ + k0) : bzero8();
    }
#pragma unroll
    for (int i = 0; i < 4; i++)
#pragma unroll
      for (int j = 0; j < 4; j++)
        acc[i][j] = __builtin_amdgcn_mfma_f32_16x16x32_bf16(af[i], bfv[j], acc[i][j], 0, 0, 0);
  }

  const float scale = 0.08838834764831845f;  // 1/sqrt(128)
#pragma unroll
  for (int i = 0; i < 4; i++) {
#pragma unroll
    for (int j = 0; j < 4; j++) {
      int m = m0 + j * 16 + l16;
#pragma unroll
      for (int r = 0; r < 4; r++) {
        int n = n0 + i * 16 + quad * 4 + r;
        if (n < N_ && m < N_) {
          size_t idx = ((size_t)bh * N_ + n) * NPAD_ + m;
          S[idx] = S[idx] + acc[i][j][r] * scale;
        }
      }
    }
  }
}

// ---------------------------------------------------------------------------
// softmax over last dim (196), one wave per row, in place (f32)
// ---------------------------------------------------------------------------
__global__ __launch_bounds__(256) void softmax_kernel(float* __restrict__ S) {
  const int bh = blockIdx.y;
  const int n = blockIdx.x * 4 + (threadIdx.x >> 6);
  const int lane = threadIdx.x & 63;
  float* row = S + ((size_t)bh * N_ + n) * NPAD_;
  float v[4];
  float mx = -1e30f;
#pragma unroll
  for (int t = 0; t < 4; t++) {
    int m = lane + t * 64;
    v[t] = (m < N_) ? row[m] : -1e30f;
    mx = fmaxf(mx, v[t]);
  }
#pragma unroll
  for (int off = 32; off > 0; off >>= 1) mx = fmaxf(mx, __shfl_xor(mx, off, 64));
  float s = 0.0f;
#pragma unroll
  for (int t = 0; t < 4; t++) {
    v[t] = __expf(v[t] - mx);
    s += v[t];
  }
#pragma unroll
  for (int off = 32; off > 0; off >>= 1) s += __shfl_xor(s, off, 64);
  const float inv = 1.0f / s;
#pragma unroll
  for (int t = 0; t < 4; t++) {
    int m = lane + t * 64;
    if (m < N_) row[m] = v[t] * inv;
  }
}

// ---------------------------------------------------------------------------
// PV: AO[b,n,h,d] = sum_m P[bh,n,m] * V[b,m,h,d]  (Vt[bh*DK+d][NPAD])
// ---------------------------------------------------------------------------
__global__ __launch_bounds__(256) void pv_kernel(const float* __restrict__ P,
                                                 const bf16* __restrict__ Vt,
                                                 bf16* __restrict__ AO) {
  const int bh = blockIdx.z;
  const int b = bh >> 3;
  const int h = bh & 7;
  const int wave = threadIdx.x >> 6;
  const int lane = threadIdx.x & 63;
  const int l16 = lane & 15;
  const int quad = lane >> 4;
  const int n0 = blockIdx.x * 128 + (wave >> 1) * 64;
  const int d0 = (wave & 1) * 64;
  const float* pbase = P + (size_t)bh * N_ * NPAD_;
  const bf16* vbase = Vt + (size_t)bh * DK_ * NPAD_ + quad * 8;

  floatx4 acc[4][4];
#pragma unroll
  for (int i = 0; i < 4; i++)
#pragma unroll
    for (int j = 0; j < 4; j++)
#pragma unroll
      for (int r = 0; r < 4; r++) acc[i][j][r] = 0.0f;

#pragma unroll
  for (int k0 = 0; k0 < NPAD_; k0 += 32) {  // masked past 196
    bf16x8 af[4], bfv[4];
#pragma unroll
    for (int i = 0; i < 4; i++) {
      int n = n0 + i * 16 + l16;
      bf16x8 a = bzero8();
      if (n < N_) {
        const float* sp = pbase + (size_t)n * NPAD_ + k0 + quad * 8;
#pragma unroll
        for (int jj = 0; jj < 8; jj++) {
          int m = k0 + quad * 8 + jj;
          float pv = (m < N_) ? sp[jj] : 0.0f;
          a[jj] = (bf16)pv;
        }
      }
      af[i] = a;
    }
#pragma unroll
    for (int j = 0; j < 4; j++) {
      int d = d0 + j * 16 + l16;
      bfv[j] = *(const bf16x8*)(vbase + (size_t)d * NPAD_ + k0);
    }
#pragma unroll
    for (int i = 0; i < 4; i++)
#pragma unroll
      for (int j = 0; j < 4; j++)
        acc[i][j] = __builtin_amdgcn_mfma_f32_16x16x32_bf16(af[i], bfv[j], acc[i][j], 0, 0, 0);
  }

#pragma unroll
  for (int i = 0; i < 4; i++) {
#pragma unroll
    for (int j = 0; j < 4; j++) {
      int d = d0 + j * 16 + l16;
#pragma unroll
      for (int r = 0; r < 4; r++) {
        int n = n0 + i * 16 + quad * 4 + r;
        if (n < N_) {
          AO[((size_t)(b * N_ + n)) * D_ + h * DK_ + d] = (bf16)acc[i][j][r];
        }
      }
    }
  }
}

// ---------------------------------------------------------------------------
extern "C" void kernel_launch(void* const* d_in, const int* in_sizes, int n_in,
                              void* d_out, int out_size, void* d_ws, size_t ws_size,
                              hipStream_t stream) {
  const float* xq = (const float*)d_in[0];
  const float* xk = (const float*)d_in[1];
  const float* xv = (const float*)d_in[2];
  const float* box = (const float*)d_in[3];
  const float* Wq = (const float*)d_in[4];
  const float* bq = (const float*)d_in[5];
  const float* Wk = (const float*)d_in[6];
  const float* bk = (const float*)d_in[7];
  const float* Wv = (const float*)d_in[8];
  const float* bv = (const float*)d_in[9];
  const float* Wo = (const float*)d_in[10];
  const float* bo = (const float*)d_in[11];
  const float* WGw = (const float*)d_in[12];
  const float* WGb = (const float*)d_in[13];

  size_t off = 0;
  char* wsc = (char*)d_ws;
  auto alloc = [&](size_t bytes) -> void* {
    void* p = wsc + off;
    off += (bytes + 255) & ~(size_t)255;
    return p;
  };
  bf16* xq_b = (bf16*)alloc((size_t)BN_ * D_ * 2);
  bf16* xk_b = (bf16*)alloc((size_t)BN_ * D_ * 2);
  bf16* xv_b = (bf16*)alloc((size_t)BN_ * D_ * 2);
  bf16* wq_b = (bf16*)alloc((size_t)D_ * D_ * 2);
  bf16* wk_b = (bf16*)alloc((size_t)D_ * D_ * 2);
  bf16* wv_b = (bf16*)alloc((size_t)D_ * D_ * 2);
  bf16* wo_b = (bf16*)alloc((size_t)D_ * D_ * 2);
  bf16* q_b = (bf16*)alloc((size_t)BN_ * D_ * 2);
  bf16* k_b = (bf16*)alloc((size_t)BN_ * D_ * 2);
  bf16* vt_b = (bf16*)alloc((size_t)BH_ * DK_ * NPAD_ * 2);
  bf16* ao_b = (bf16*)alloc((size_t)BN_ * D_ * 2);
  float* S = (float*)alloc((size_t)BH_ * N_ * NPAD_ * 4);

  const int n4x = BN_ * D_ / 4;  // 1605632
  const int n4w = D_ * D_ / 4;   // 262144
  cvt_kernel<<<n4x / 256, 256, 0, stream>>>(xq, xq_b, n4x);
  cvt_kernel<<<n4x / 256, 256, 0, stream>>>(xk, xk_b, n4x);
  cvt_kernel<<<n4x / 256, 256, 0, stream>>>(xv, xv_b, n4x);
  cvt_kernel<<<n4w / 256, 256, 0, stream>>>(Wq, wq_b, n4w);
  cvt_kernel<<<n4w / 256, 256, 0, stream>>>(Wk, wk_b, n4w);
  cvt_kernel<<<n4w / 256, 256, 0, stream>>>(Wv, wv_b, n4w);
  cvt_kernel<<<n4w / 256, 256, 0, stream>>>(Wo, wo_b, n4w);

  geo_kernel<<<(B_ * N_ * N_) / 256, 256, 0, stream>>>(box, WGw, WGb, S);

  dim3 gproj(BN_ / 128, D_ / 128, 1);  // (49, 8)
  gemm_nt<0><<<gproj, 256, 0, stream>>>(xq_b, wq_b, bq, q_b, BN_, D_, D_);
  gemm_nt<0><<<gproj, 256, 0, stream>>>(xk_b, wk_b, bk, k_b, BN_, D_, D_);
  gemm_nt<2><<<gproj, 256, 0, stream>>>(xv_b, wv_b, bv, vt_b, BN_, D_, D_);

  scores_kernel<<<dim3(2, 2, BH_), 256, 0, stream>>>(q_b, k_b, S);
  softmax_kernel<<<dim3(49, BH_, 1), 256, 0, stream>>>(S);
  pv_kernel<<<dim3(2, 1, BH_), 256, 0, stream>>>(S, vt_b, ao_b);

  gemm_nt<1><<<gproj, 256, 0, stream>>>(ao_b, wo_b, bo, d_out, BN_, D_, D_);
}

// Round 3
// 378.933 us; speedup vs baseline: 1.4491x; 1.0797x over previous
//
#include <hip/hip_runtime.h>
#include <hip/hip_bf16.h>

typedef __bf16 bf16;
typedef bf16 bf16x8 __attribute__((ext_vector_type(8)));
typedef bf16 bf16x4 __attribute__((ext_vector_type(4)));
typedef float floatx4 __attribute__((ext_vector_type(4)));

#define B_ 32
#define N_ 196
#define H_ 8
#define D_ 1024
#define DK_ 128
#define BN_ (B_ * N_)   // 6272
#define BH_ (B_ * H_)   // 256
#define NPAD_ 224       // padded N for S rows / Vt cols
#define PSTRIDE_ 232    // LDS P-tile col stride (16B aligned, bank-spread)

typedef __attribute__((address_space(3))) unsigned int lds_uint;
typedef const __attribute__((address_space(1))) unsigned int glb_uint;

__device__ __forceinline__ void async_copy16(const bf16* g, bf16* l) {
  __builtin_amdgcn_global_load_lds((glb_uint*)g, (lds_uint*)l, 16, 0, 0);
}

__device__ __forceinline__ bf16x8 bzero8() {
  bf16x8 z;
#pragma unroll
  for (int i = 0; i < 8; i++) z[i] = (bf16)0.0f;
  return z;
}

// ---------------------------------------------------------------------------
// f32 -> bf16 convert
// ---------------------------------------------------------------------------
__global__ __launch_bounds__(256) void cvt_kernel(const float* __restrict__ src,
                                                  bf16* __restrict__ dst, int n4) {
  int i = blockIdx.x * 256 + threadIdx.x;
  if (i >= n4) return;
  float4 v = ((const float4*)src)[i];
  bf16x4 o;
  o[0] = (bf16)v.x;
  o[1] = (bf16)v.y;
  o[2] = (bf16)v.z;
  o[3] = (bf16)v.w;
  *(bf16x4*)(dst + (size_t)i * 4) = o;
}

// ---------------------------------------------------------------------------
// Geometry bias: S[b,h,n,m] = log(max(relu(geo(n,m) . WG_w[h] + WG_b[h]), 1e-6))
// ---------------------------------------------------------------------------
__global__ __launch_bounds__(256) void geo_kernel(const float* __restrict__ box,
                                                  const float* __restrict__ WGw,
                                                  const float* __restrict__ WGb,
                                                  float* __restrict__ S) {
  __shared__ float4 wsh[128];
  if (threadIdx.x < 128) wsh[threadIdx.x] = ((const float4*)WGw)[threadIdx.x];
  __syncthreads();

  int tid = blockIdx.x * 256 + threadIdx.x;
  int b = tid / (N_ * N_);
  int rem = tid - b * (N_ * N_);
  int n = rem / N_;
  int m = rem - n * N_;

  float4 bn = ((const float4*)box)[b * N_ + n];
  float4 bm = ((const float4*)box)[b * N_ + m];
  float cxn = (bn.x + bn.z) * 0.5f, cyn = (bn.y + bn.w) * 0.5f;
  float wn = bn.z - bn.x + 1.0f, hn = bn.w - bn.y + 1.0f;
  float cxm = (bm.x + bm.z) * 0.5f, cym = (bm.y + bm.w) * 0.5f;
  float wm = bm.z - bm.x + 1.0f, hm = bm.w - bm.y + 1.0f;

  float pos[4];
  pos[0] = __logf(fmaxf(fabsf((cxn - cxm) / wn), 1e-3f));
  pos[1] = __logf(fmaxf(fabsf((cyn - cym) / hn), 1e-3f));
  pos[2] = __logf(wn / wm);
  pos[3] = __logf(hn / hm);

  const float dims[8] = {1.0f,          0.4216965034f, 0.1778279410f, 0.0749894209f,
                         0.0316227766f, 0.0133352143f, 0.0056234133f, 0.0023713737f};
  float feat[64];
#pragma unroll
  for (int p = 0; p < 4; p++) {
#pragma unroll
    for (int f = 0; f < 8; f++) {
      float a = 100.0f * pos[p] * dims[f];
      feat[p * 8 + f] = __sinf(a);
      feat[32 + p * 8 + f] = __cosf(a);
    }
  }
#pragma unroll
  for (int hh = 0; hh < 8; hh++) {
    float accv = WGb[hh];
#pragma unroll
    for (int g4 = 0; g4 < 16; g4++) {
      float4 wv = wsh[hh * 16 + g4];
      accv += feat[g4 * 4 + 0] * wv.x + feat[g4 * 4 + 1] * wv.y +
              feat[g4 * 4 + 2] * wv.z + feat[g4 * 4 + 3] * wv.w;
    }
    S[((size_t)((b * H_ + hh) * N_ + n)) * NPAD_ + m] = __logf(fmaxf(accv, 1e-6f));
  }
}

// ---------------------------------------------------------------------------
// NT GEMM w/ LDS staging (m97 structure), 128x128 tile, BK=32.
// MODE 0: bf16 row-major; MODE 1: f32 row-major; MODE 2: Vt[(bh)*DK+d][NPAD]
// ---------------------------------------------------------------------------
template <int MODE>
__global__ __launch_bounds__(256) void gemm_nt(const bf16* __restrict__ A,
                                               const bf16* __restrict__ W,
                                               const float* __restrict__ bias,
                                               void* __restrict__ Cout, int M, int K,
                                               int Nd) {
  __shared__ bf16 As[128 * 32];
  __shared__ bf16 Bs[128 * 32];

  const int wave = threadIdx.x >> 6;
  const int lane = threadIdx.x & 63;
  const int l16 = lane & 15;
  const int quad = lane >> 4;

  const bf16* gA = A + (size_t)blockIdx.x * 128 * K;
  const bf16* gB = W + (size_t)blockIdx.y * 128 * K;

  const int srow = lane >> 2;
  const int scol = (lane & 3) * 8;
  const int seg0 = wave * 2;
  const size_t gOffA0 = (size_t)(seg0 * 16 + srow) * K + scol;
  const size_t gOffA1 = (size_t)(seg0 * 16 + 16 + srow) * K + scol;
  bf16* lA0 = As + seg0 * 512 + lane * 8;
  bf16* lA1 = As + (seg0 + 1) * 512 + lane * 8;
  bf16* lB0 = Bs + seg0 * 512 + lane * 8;
  bf16* lB1 = Bs + (seg0 + 1) * 512 + lane * 8;

  floatx4 acc[4][4];
#pragma unroll
  for (int i = 0; i < 4; i++)
#pragma unroll
    for (int j = 0; j < 4; j++)
#pragma unroll
      for (int r = 0; r < 4; r++) acc[i][j][r] = 0.0f;

  async_copy16(gA + gOffA0, lA0);
  async_copy16(gA + gOffA1, lA1);
  async_copy16(gB + gOffA0, lB0);
  async_copy16(gB + gOffA1, lB1);

  const bf16* rA = As + ((wave >> 1) * 64 + l16) * 32 + quad * 8;
  const bf16* rB = Bs + ((wave & 1) * 64 + l16) * 32 + quad * 8;

  for (int k0 = 0; k0 < K; k0 += 32) {
    __syncthreads();
    bf16x8 af[4], bfv[4];
#pragma unroll
    for (int i = 0; i < 4; i++) af[i] = *(const bf16x8*)(rA + i * 16 * 32);
#pragma unroll
    for (int j = 0; j < 4; j++) bfv[j] = *(const bf16x8*)(rB + j * 16 * 32);
    __syncthreads();
    if (k0 + 32 < K) {
      const bf16* gAn = gA + k0 + 32;
      const bf16* gBn = gB + k0 + 32;
      async_copy16(gAn + gOffA0, lA0);
      async_copy16(gAn + gOffA1, lA1);
      async_copy16(gBn + gOffA0, lB0);
      async_copy16(gBn + gOffA1, lB1);
    }
#pragma unroll
    for (int i = 0; i < 4; i++)
#pragma unroll
      for (int j = 0; j < 4; j++)
        acc[i][j] = __builtin_amdgcn_mfma_f32_16x16x32_bf16(af[i], bfv[j], acc[i][j], 0, 0, 0);
  }

  const int m0 = blockIdx.x * 128 + (wave >> 1) * 64;
  const int n0 = blockIdx.y * 128 + (wave & 1) * 64;
#pragma unroll
  for (int j = 0; j < 4; j++) {
    const int col = n0 + j * 16 + l16;
    const float bv = bias[col];
#pragma unroll
    for (int i = 0; i < 4; i++) {
#pragma unroll
      for (int r = 0; r < 4; r++) {
        const int row = m0 + i * 16 + quad * 4 + r;
        float v = acc[i][j][r] + bv;
        if (MODE == 0) {
          ((bf16*)Cout)[(size_t)row * Nd + col] = (bf16)v;
        } else if (MODE == 1) {
          ((float*)Cout)[(size_t)row * Nd + col] = v;
        } else {
          int b = row / N_;
          int n = row - b * N_;
          int h = col >> 7;
          int d = col & (DK_ - 1);
          ((bf16*)Cout)[((size_t)((b * H_ + h) * DK_ + d)) * NPAD_ + n] = (bf16)v;
        }
      }
    }
  }
}

// ---------------------------------------------------------------------------
// Fused attention: per block = one (b,h) x 64 Q-rows.
// QK^T (S in regs, 14 j-frags) + bias read + softmax (shfl over 16-lane col
// groups) + P->LDS (layout transform) + PV -> AO.  No S round-trip to HBM.
// grid: 1024 flat; swizzled so the 4 row-tiles of a bh share an XCD.
// ---------------------------------------------------------------------------
__global__ __launch_bounds__(256) void attn_kernel(const bf16* __restrict__ Q,
                                                   const bf16* __restrict__ Kmat,
                                                   const bf16* __restrict__ Vt,
                                                   const float* __restrict__ Sb,
                                                   bf16* __restrict__ AO) {
  __shared__ bf16 Pl[4 * 16 * PSTRIDE_];

  const int f = blockIdx.x;
  const int tile = (f >> 3) & 3;                 // blocks {i,i+8,i+16,i+24} share bh? no:
  const int bh = (f & 7) | ((f >> 5) << 3);      // tiles of one bh are 8 apart -> same XCD (round-robin)
  const int b = bh >> 3;
  const int h = bh & 7;
  const int wave = threadIdx.x >> 6;
  const int lane = threadIdx.x & 63;
  const int l16 = lane & 15;
  const int quad = lane >> 4;
  const int nrb = tile * 64 + wave * 16;         // this wave's 16 rows

  // ---- QK^T ----
  floatx4 S[14];
#pragma unroll
  for (int j = 0; j < 14; j++)
#pragma unroll
    for (int r = 0; r < 4; r++) S[j][r] = 0.0f;

  const int na = nrb + l16;
  const bool nav = na < N_;
  const bf16* aptr = Q + ((size_t)(b * N_ + (nav ? na : 0))) * D_ + h * DK_ + quad * 8;
  bf16x8 afr[4];
#pragma unroll
  for (int kk = 0; kk < 4; kk++) afr[kk] = nav ? *(const bf16x8*)(aptr + kk * 32) : bzero8();

#pragma unroll
  for (int j = 0; j < 14; j++) {
    const int m = j * 16 + l16;
    const bool mv = m < N_;
    const bf16* kp = Kmat + ((size_t)(b * N_ + (mv ? m : 0))) * D_ + h * DK_ + quad * 8;
#pragma unroll
    for (int kk = 0; kk < 4; kk++) {
      bf16x8 bb = mv ? *(const bf16x8*)(kp + kk * 32) : bzero8();
      S[j] = __builtin_amdgcn_mfma_f32_16x16x32_bf16(afr[kk], bb, S[j], 0, 0, 0);
    }
  }

  // ---- scale + bias + mask ----
  const float scale = 0.08838834764831845f;  // 1/sqrt(128)
  const float* bbase = Sb + ((size_t)bh * N_) * NPAD_;
#pragma unroll
  for (int r = 0; r < 4; r++) {
    const int n = nrb + quad * 4 + r;
    const bool nv = n < N_;
#pragma unroll
    for (int j = 0; j < 14; j++) {
      const int m = j * 16 + l16;
      float v = -1e30f;
      if (nv && m < N_) v = S[j][r] * scale + bbase[(size_t)n * NPAD_ + m];
      S[j][r] = v;
    }
  }

  // ---- softmax over cols (reduce across the 16-lane l16 group) ----
  float inv[4];
#pragma unroll
  for (int r = 0; r < 4; r++) {
    float mx = S[0][r];
#pragma unroll
    for (int j = 1; j < 14; j++) mx = fmaxf(mx, S[j][r]);
#pragma unroll
    for (int off = 1; off < 16; off <<= 1) mx = fmaxf(mx, __shfl_xor(mx, off, 64));
    float sum = 0.0f;
#pragma unroll
    for (int j = 0; j < 14; j++) {
      float e = __expf(S[j][r] - mx);
      S[j][r] = e;
      sum += e;
    }
#pragma unroll
    for (int off = 1; off < 16; off <<= 1) sum += __shfl_xor(sum, off, 64);
    inv[r] = 1.0f / sum;
  }

  // ---- P -> LDS (C-layout -> A-layout transform), bf16 ----
  bf16* pw = Pl + wave * 16 * PSTRIDE_;
#pragma unroll
  for (int r = 0; r < 4; r++) {
#pragma unroll
    for (int j = 0; j < 14; j++) {
      pw[(quad * 4 + r) * PSTRIDE_ + j * 16 + l16] = (bf16)S[j][r];
    }
  }
  __syncthreads();

  // ---- PV ----
  floatx4 O[8];
#pragma unroll
  for (int j2 = 0; j2 < 8; j2++)
#pragma unroll
    for (int r = 0; r < 4; r++) O[j2][r] = 0.0f;

  const bf16* vbase = Vt + (size_t)bh * DK_ * NPAD_ + quad * 8;
  const bf16* pr = pw + l16 * PSTRIDE_ + quad * 8;
#pragma unroll
  for (int k0 = 0; k0 < NPAD_; k0 += 32) {
    bf16x8 a = *(const bf16x8*)(pr + k0);
#pragma unroll
    for (int j2 = 0; j2 < 8; j2++) {
      bf16x8 bb = *(const bf16x8*)(vbase + (size_t)(j2 * 16 + l16) * NPAD_ + k0);
      O[j2] = __builtin_amdgcn_mfma_f32_16x16x32_bf16(a, bb, O[j2], 0, 0, 0);
    }
  }

  // ---- epilogue: scale by 1/l, store ----
#pragma unroll
  for (int r = 0; r < 4; r++) {
    const int n = nrb + quad * 4 + r;
    if (n < N_) {
#pragma unroll
      for (int j2 = 0; j2 < 8; j2++) {
        AO[((size_t)(b * N_ + n)) * D_ + h * DK_ + j2 * 16 + l16] = (bf16)(O[j2][r] * inv[r]);
      }
    }
  }
}

// ---------------------------------------------------------------------------
extern "C" void kernel_launch(void* const* d_in, const int* in_sizes, int n_in,
                              void* d_out, int out_size, void* d_ws, size_t ws_size,
                              hipStream_t stream) {
  const float* xq = (const float*)d_in[0];
  const float* xk = (const float*)d_in[1];
  const float* xv = (const float*)d_in[2];
  const float* box = (const float*)d_in[3];
  const float* Wq = (const float*)d_in[4];
  const float* bq = (const float*)d_in[5];
  const float* Wk = (const float*)d_in[6];
  const float* bk = (const float*)d_in[7];
  const float* Wv = (const float*)d_in[8];
  const float* bv = (const float*)d_in[9];
  const float* Wo = (const float*)d_in[10];
  const float* bo = (const float*)d_in[11];
  const float* WGw = (const float*)d_in[12];
  const float* WGb = (const float*)d_in[13];

  size_t off = 0;
  char* wsc = (char*)d_ws;
  auto alloc = [&](size_t bytes) -> void* {
    void* p = wsc + off;
    off += (bytes + 255) & ~(size_t)255;
    return p;
  };
  bf16* xq_b = (bf16*)alloc((size_t)BN_ * D_ * 2);
  bf16* xk_b = (bf16*)alloc((size_t)BN_ * D_ * 2);
  bf16* xv_b = (bf16*)alloc((size_t)BN_ * D_ * 2);
  bf16* wq_b = (bf16*)alloc((size_t)D_ * D_ * 2);
  bf16* wk_b = (bf16*)alloc((size_t)D_ * D_ * 2);
  bf16* wv_b = (bf16*)alloc((size_t)D_ * D_ * 2);
  bf16* wo_b = (bf16*)alloc((size_t)D_ * D_ * 2);
  bf16* q_b = (bf16*)alloc((size_t)BN_ * D_ * 2);
  bf16* k_b = (bf16*)alloc((size_t)BN_ * D_ * 2);
  bf16* vt_b = (bf16*)alloc((size_t)BH_ * DK_ * NPAD_ * 2);
  bf16* ao_b = (bf16*)alloc((size_t)BN_ * D_ * 2);
  float* S = (float*)alloc((size_t)BH_ * N_ * NPAD_ * 4);

  const int n4x = BN_ * D_ / 4;
  const int n4w = D_ * D_ / 4;
  cvt_kernel<<<n4x / 256, 256, 0, stream>>>(xq, xq_b, n4x);
  cvt_kernel<<<n4x / 256, 256, 0, stream>>>(xk, xk_b, n4x);
  cvt_kernel<<<n4x / 256, 256, 0, stream>>>(xv, xv_b, n4x);
  cvt_kernel<<<n4w / 256, 256, 0, stream>>>(Wq, wq_b, n4w);
  cvt_kernel<<<n4w / 256, 256, 0, stream>>>(Wk, wk_b, n4w);
  cvt_kernel<<<n4w / 256, 256, 0, stream>>>(Wv, wv_b, n4w);
  cvt_kernel<<<n4w / 256, 256, 0, stream>>>(Wo, wo_b, n4w);

  geo_kernel<<<(B_ * N_ * N_) / 256, 256, 0, stream>>>(box, WGw, WGb, S);

  // zero Vt so its pad columns (n in [196,224)) are 0, not poison
  hipMemsetAsync(vt_b, 0, (size_t)BH_ * DK_ * NPAD_ * 2, stream);

  dim3 gproj(BN_ / 128, D_ / 128, 1);
  gemm_nt<0><<<gproj, 256, 0, stream>>>(xq_b, wq_b, bq, q_b, BN_, D_, D_);
  gemm_nt<0><<<gproj, 256, 0, stream>>>(xk_b, wk_b, bk, k_b, BN_, D_, D_);
  gemm_nt<2><<<gproj, 256, 0, stream>>>(xv_b, wv_b, bv, vt_b, BN_, D_, D_);

  attn_kernel<<<1024, 256, 0, stream>>>(q_b, k_b, vt_b, S, ao_b);

  gemm_nt<1><<<gproj, 256, 0, stream>>>(ao_b, wo_b, bo, d_out, BN_, D_, D_);
}